// Round 17
// baseline (128.326 us; speedup 1.0000x reference)
//
#include <hip/hip_runtime.h>
#include <math.h>
#include <float.h>

#define N_ROWS 65536
#define K_CODES 1024
#define C_DIM 64
#define BLK 256
#define TMARGIN 0.02f

typedef short s16x8 __attribute__((ext_vector_type(8)));
typedef float f32x4 __attribute__((ext_vector_type(4)));
typedef float f32x4u __attribute__((ext_vector_type(4), aligned(4)));

// d_out layout (float32), outputs concatenated in return order:
// [loss(1)][quantized_st(N*C)][perplexity(1)][indices(N)][avg_probs(K)]
#define OUT_LOSS 0
#define OUT_Q 1
#define OUT_PPL (1 + N_ROWS * C_DIM)     // 4194305
#define OUT_IDX (OUT_PPL + 1)            // 4194306
#define OUT_AVG (OUT_IDX + N_ROWS)       // 4259842

// d_ws layout (4-byte dword offsets), total 395,776 dw = 1.58 MB
#define WS_HIST 0                        // uint[1024]
#define WS_EE 1024                       // float[1024]
#define WS_LOSSP 2048                    // float[256]
#define WS_PB1 2560                      // float[2*N_ROWS]  -> 133632
#define WS_PB2 133632                    // float[2*N_ROWS]  -> 264704
#define WS_PI1 264704                    // ushort[2*N_ROWS] -> 330240
#define WS_BS_D 330240                   // ushort[1024*128] -> 395776

__device__ __forceinline__ unsigned short bf16_rne(float f) {
    unsigned u = __float_as_uint(f);
    return (unsigned short)((u + 0x7FFFu + ((u >> 16) & 1u)) >> 16);
}
__device__ __forceinline__ float bf16_val(unsigned short h) {
    return __uint_as_float(((unsigned)h) << 16);
}

// Kernel A: coalesced codebook split + hist zero + ee (verified order)
__global__ __launch_bounds__(BLK) void vq_prep(
    const float* __restrict__ emb, float* __restrict__ ee,
    unsigned* __restrict__ hist, unsigned short* __restrict__ bs) {
    const int gid = blockIdx.x * BLK + threadIdx.x;   // [0, 65536)
    {
        float e = emb[gid];                            // coalesced
        unsigned short h = bf16_rne(e);
        float m = e - bf16_val(h);
        int k = gid >> 6, c = gid & 63;
        bs[(size_t)k * 128 + c] = h;
        bs[(size_t)k * 128 + 64 + c] = bf16_rne(m);
    }
    if (gid < K_CODES) {
        hist[gid] = 0u;
        const float* ev = emb + (size_t)gid * C_DIM;
        float s0 = 0.f, s1 = 0.f, s2 = 0.f, s3 = 0.f;
#pragma unroll
        for (int i = 0; i < 16; ++i) {
            float a = ev[4 * i + 0], b = ev[4 * i + 1];
            float c = ev[4 * i + 2], d = ev[4 * i + 3];
            s0 = fmaf(a, a, s0);
            s1 = fmaf(b, b, s1);
            s2 = fmaf(c, c, s2);
            s3 = fmaf(d, d, s3);
        }
        ee[gid] = (s0 + s1) + (s2 + s3);
    }
}

// async global->LDS, 16B per lane; LDS dest is wave-uniform base + lane*16
#define GLD16(gsrc, ldst)                                                     \
    __builtin_amdgcn_global_load_lds(                                         \
        (const __attribute__((address_space(1))) unsigned int*)(gsrc),        \
        (__attribute__((address_space(3))) unsigned int*)(ldst), 16, 0, 0)

// Kernel B: MFMA distances — verified R16 numerics (K-split x2, XOR swizzle,
// 4x3-MFMA chains, fmed3 2nd-best). Single change vs R16: 64-code phases
// (4 sub-tiles, 4 GLD16/phase) -> 8 barriers per block instead of 16.
__global__ __launch_bounds__(BLK, 4) void vq_mfma(
    const float* __restrict__ x, const unsigned short* __restrict__ bs,
    const float* __restrict__ ee, float* __restrict__ pb1,
    float* __restrict__ pb2, unsigned short* __restrict__ pi1) {
    __shared__ __align__(16) unsigned char sB[2][16384];  // 2 x (64 codes x 256B)
    __shared__ float sEE[512];

    const int tid = threadIdx.x;
    const int wave = tid >> 6;
    const int lane = tid & 63;
    const int lrow = lane & 15;          // A-row / C-col lane index
    const int lq = lane >> 4;            // k-quarter / C row-group
    const int rowbase = blockIdx.x * 128 + wave * 32;
    const int half = blockIdx.y;
    const int kbase = half * (K_CODES / 2);

    sEE[tid] = ee[kbase + tid];
    sEE[tid + 256] = ee[kbase + tid + 256];

    // per-thread pre-swizzled global source for B staging (rule #21 pattern).
    // thread tid fills LDS bytes [tid*16,+16) of each 4KB sub-stage (16 rows).
    const int srow = tid >> 4;
    const int sz8 = ((tid & 15) ^ (srow & 7)) * 8;       // ushort offset
    const unsigned short* sbase = bs + (size_t)(kbase + srow) * 128 + sz8;

    // ---- A fragments for two row-sets (P: rows 0..15, Q: rows 16..31) ----
    s16x8 ph0, ph1, pm0, pm1, qh0, qh1, qm0, qm1;
    {
        const float* xp = x + (size_t)(rowbase + lrow) * C_DIM + lq * 8;
        const float* xq = xp + 16 * C_DIM;
#pragma unroll
        for (int j = 0; j < 8; ++j) {
            float a0 = xp[j], a1 = xp[32 + j];
            float b0 = xq[j], b1v = xq[32 + j];
            unsigned short h;
            h = bf16_rne(a0); ph0[j] = (short)h; pm0[j] = (short)bf16_rne(a0 - bf16_val(h));
            h = bf16_rne(a1); ph1[j] = (short)h; pm1[j] = (short)bf16_rne(a1 - bf16_val(h));
            h = bf16_rne(b0); qh0[j] = (short)h; qm0[j] = (short)bf16_rne(b0 - bf16_val(h));
            h = bf16_rne(b1v); qh1[j] = (short)h; qm1[j] = (short)bf16_rne(b1v - bf16_val(h));
        }
    }

    float b1[8], b2[8];
    int i1[8];
#pragma unroll
    for (int q = 0; q < 8; ++q) { b1[q] = FLT_MAX; b2[q] = FLT_MAX; i1[q] = 0; }

    // swizzled ds_read byte offsets (within a 4KB sub-tile)
    const int rb = lrow * 256;
    const int swz = (lrow & 7) << 4;
    const int o0 = rb + ((0 + lq * 16) ^ swz);
    const int o1 = rb + ((64 + lq * 16) ^ swz);
    const int o2 = rb + ((128 + lq * 16) ^ swz);
    const int o3 = rb + ((192 + lq * 16) ^ swz);

    // prologue: stage phase 0 (64 codes = 16KB, four 4KB sub-stages)
#pragma unroll
    for (int s = 0; s < 4; ++s)
        GLD16(sbase + s * 2048, &sB[0][s * 4096 + wave * 1024]);
    __syncthreads();

    int buf = 0;
    for (int t = 0; t < 8; ++t) {           // 8 phases of 64 codes per half
        if (t + 1 < 8) {
#pragma unroll
            for (int s = 0; s < 4; ++s)
                GLD16(sbase + (size_t)(t + 1) * 8192 + s * 2048,
                      &sB[buf ^ 1][s * 4096 + wave * 1024]);
        }

#pragma unroll
        for (int sub = 0; sub < 4; ++sub) {  // ascending code order kept
            const unsigned char* bb = &sB[buf][sub * 4096];
            s16x8 c0 = *(const s16x8*)(bb + o0);
            s16x8 c1 = *(const s16x8*)(bb + o1);
            s16x8 c2 = *(const s16x8*)(bb + o2);
            s16x8 c3 = *(const s16x8*)(bb + o3);
            float eek = sEE[t * 64 + sub * 16 + lrow];

            // x.e = xh.eh + xh.em + xm.eh, split by k-half: 4 chains of 3 MFMAs
            f32x4 z = {0.f, 0.f, 0.f, 0.f};
            f32x4 pa = __builtin_amdgcn_mfma_f32_16x16x32_bf16(ph0, c0, z, 0, 0, 0);
            f32x4 pb = __builtin_amdgcn_mfma_f32_16x16x32_bf16(ph1, c1, z, 0, 0, 0);
            f32x4 qa = __builtin_amdgcn_mfma_f32_16x16x32_bf16(qh0, c0, z, 0, 0, 0);
            f32x4 qb = __builtin_amdgcn_mfma_f32_16x16x32_bf16(qh1, c1, z, 0, 0, 0);
            pa = __builtin_amdgcn_mfma_f32_16x16x32_bf16(ph0, c2, pa, 0, 0, 0);
            pb = __builtin_amdgcn_mfma_f32_16x16x32_bf16(ph1, c3, pb, 0, 0, 0);
            qa = __builtin_amdgcn_mfma_f32_16x16x32_bf16(qh0, c2, qa, 0, 0, 0);
            qb = __builtin_amdgcn_mfma_f32_16x16x32_bf16(qh1, c3, qb, 0, 0, 0);
            pa = __builtin_amdgcn_mfma_f32_16x16x32_bf16(pm0, c0, pa, 0, 0, 0);
            pb = __builtin_amdgcn_mfma_f32_16x16x32_bf16(pm1, c1, pb, 0, 0, 0);
            qa = __builtin_amdgcn_mfma_f32_16x16x32_bf16(qm0, c0, qa, 0, 0, 0);
            qb = __builtin_amdgcn_mfma_f32_16x16x32_bf16(qm1, c1, qb, 0, 0, 0);

            const int code = kbase + t * 64 + sub * 16 + lrow;
#pragma unroll
            for (int q = 0; q < 4; ++q) {
                float sP = fmaf(-2.0f, pa[q] + pb[q], eek);
                b2[q] = __builtin_amdgcn_fmed3f(b1[q], b2[q], sP);  // new 2nd
                i1[q] = (sP < b1[q]) ? code : i1[q];      // strict <, asc code
                b1[q] = fminf(b1[q], sP);

                float sQ = fmaf(-2.0f, qa[q] + qb[q], eek);
                b2[4 + q] = __builtin_amdgcn_fmed3f(b1[4 + q], b2[4 + q], sQ);
                i1[4 + q] = (sQ < b1[4 + q]) ? code : i1[4 + q];
                b1[4 + q] = fminf(b1[4 + q], sQ);
            }
        }

        __syncthreads();
        buf ^= 1;
    }

    // cross-lane argmin over the 16 code-lanes (lex (score, idx)), keep top-2
#pragma unroll
    for (int m = 1; m <= 8; m <<= 1) {
#pragma unroll
        for (int q = 0; q < 8; ++q) {
            float ca = __shfl_xor(b1[q], m, 64);
            float cb = __shfl_xor(b2[q], m, 64);
            int ci = __shfl_xor(i1[q], m, 64);
            if (ca < b1[q] || (ca == b1[q] && ci < i1[q])) {
                b2[q] = fminf(b1[q], cb);
                b1[q] = ca;
                i1[q] = ci;
            } else {
                b2[q] = fminf(b2[q], ca);
            }
        }
    }

    if (lrow == 0) {
#pragma unroll
        for (int q = 0; q < 8; ++q) {
            int r = rowbase + (q >> 2) * 16 + lq * 4 + (q & 3);
            pb1[half * N_ROWS + r] = b1[q];
            pb2[half * N_ROWS + r] = b2[q];
            pi1[half * N_ROWS + r] = (unsigned short)i1[q];
        }
    }
}

// Kernel C (fused): merge halves + inline block-cooperative exact refine +
// histogram + indices + float4-vectorized quantized_st + loss partial.
__global__ __launch_bounds__(BLK) void vq_fused(
    const float* __restrict__ x, const float* __restrict__ emb,
    const float* __restrict__ ee, const float* __restrict__ pb1,
    const float* __restrict__ pb2, const unsigned short* __restrict__ pi1,
    unsigned* __restrict__ hist, float* __restrict__ lossp,
    float* __restrict__ out) {
    __shared__ int sIdx[BLK];
    __shared__ unsigned sHist[K_CODES];
    __shared__ float sRed[BLK / 64];
    __shared__ int sQ[BLK];
    __shared__ unsigned sQn;
    __shared__ float sWb[4];
    __shared__ int sWi[4];

    const int t = threadIdx.x;
    const int w = t >> 6;
    const int lane = t & 63;
    const int base = blockIdx.x * BLK;

    if (t == 0) sQn = 0u;
    for (int i = t; i < K_CODES; i += BLK) sHist[i] = 0u;

    // merge the two K-halves (verified logic: strict <, half0 wins ties)
    const int r = base + t;
    float a1 = pb1[r], a2 = pb2[r];
    int ai = pi1[r];
    float c1 = pb1[N_ROWS + r], c2 = pb2[N_ROWS + r];
    int ci = pi1[N_ROWS + r];
    bool bw = c1 < a1;
    float s1 = bw ? c1 : a1;
    int idx = bw ? ci : ai;
    float s2 = bw ? fminf(c2, a1) : fminf(a2, c1);
    sIdx[t] = idx;
    __syncthreads();                       // sQn/sHist/sIdx visible
    if (s2 - s1 < TMARGIN) {               // uncertain -> local queue
        unsigned p = atomicAdd(&sQn, 1u);
        sQ[p] = t;
    }
    __syncthreads();

    // inline exact re-argmin for queued rows (verified fp32 path; wave w owns
    // codes w*256 + lane*4 + j; lex block-reduce -> first-min semantics)
    const unsigned m = sQn;
    for (unsigned qi = 0; qi < m; ++qi) {
        const int rl = sQ[qi];
        const float4* xv = (const float4*)(x + (size_t)(base + rl) * C_DIM);
        float best = FLT_MAX;
        int bi = 0;
#pragma unroll
        for (int j = 0; j < 4; ++j) {
            const int k = w * 256 + lane * 4 + j;
            const float4* evv = (const float4*)(emb + (size_t)k * C_DIM);
            float d0 = 0.f, d1 = 0.f, d2 = 0.f, d3 = 0.f;
#pragma unroll
            for (int i = 0; i < 16; ++i) {
                float4 xi = xv[i];
                float4 e = evv[i];
                d0 = fmaf(xi.x, e.x, d0);
                d1 = fmaf(xi.y, e.y, d1);
                d2 = fmaf(xi.z, e.z, d2);
                d3 = fmaf(xi.w, e.w, d3);
            }
            float dot = (d0 + d1) + (d2 + d3);
            float s = fmaf(-2.0f, dot, ee[k]);
            if (s < best) { best = s; bi = k; }      // strict <: first-min
        }
#pragma unroll
        for (int mm = 1; mm <= 32; mm <<= 1) {
            float ob = __shfl_xor(best, mm, 64);
            int oi = __shfl_xor(bi, mm, 64);
            if (ob < best || (ob == best && oi < bi)) { best = ob; bi = oi; }
        }
        if (lane == 0) { sWb[w] = best; sWi[w] = bi; }
        __syncthreads();
        if (t == 0) {
            float b = sWb[0];
            int i = sWi[0];
#pragma unroll
            for (int w2 = 1; w2 < 4; ++w2) {
                if (sWb[w2] < b || (sWb[w2] == b && sWi[w2] < i)) {
                    b = sWb[w2];
                    i = sWi[w2];
                }
            }
            sIdx[rl] = i;
        }
        __syncthreads();
    }

    // indices out + histogram (final indices)
    const int bidx = sIdx[t];
    out[OUT_IDX + r] = (float)bidx;
    atomicAdd(&sHist[bidx], 1u);
    __syncthreads();
    for (int i = t; i < K_CODES; i += BLK) {
        unsigned c = sHist[i];
        if (c) atomicAdd(&hist[i], c);
    }

    // epilogue: quantized_st + loss partial, float4-vectorized:
    // 16 threads per row x 4 floats; 16 iterations (was 64 scalar).
    float lsum = 0.f;
    const int c4 = (t & 15) * 4;           // column (float4 granularity)
    const int rg4 = t >> 4;                // row group 0..15
    for (int it = 0; it < 16; ++it) {
        const int rl = it * 16 + rg4;
        const int rr = base + rl;
        const int bi = sIdx[rl];           // uniform per 16-lane group
        float4 xv = *(const float4*)(x + (size_t)rr * C_DIM + c4);
        float4 qv = *(const float4*)(emb + (size_t)bi * C_DIM + c4);
        float dx = qv.x - xv.x, dy = qv.y - xv.y;
        float dz = qv.z - xv.z, dw = qv.w - xv.w;
        f32x4u o;
        o[0] = xv.x + dx; o[1] = xv.y + dy;
        o[2] = xv.z + dz; o[3] = xv.w + dw;          // straight-through
        *(f32x4u*)(out + OUT_Q + (size_t)rr * C_DIM + c4) = o;
        lsum = fmaf(dx, dx, lsum);
        lsum = fmaf(dy, dy, lsum);
        lsum = fmaf(dz, dz, lsum);
        lsum = fmaf(dw, dw, lsum);
    }
#pragma unroll
    for (int o = 32; o > 0; o >>= 1) lsum += __shfl_down(lsum, o, 64);
    if ((t & 63) == 0) sRed[t >> 6] = lsum;
    __syncthreads();
    if (t == 0) lossp[blockIdx.x] = (sRed[0] + sRed[1]) + (sRed[2] + sRed[3]);
}

// Kernel D: avg_probs, perplexity, loss finalization
__global__ void vq_final(const unsigned* __restrict__ hist,
                         const float* __restrict__ lossp,
                         float* __restrict__ out) {
    __shared__ float sP[K_CODES];
    __shared__ float sL[K_CODES];
    const int t = threadIdx.x;
    float p = (float)hist[t] * (1.0f / (float)N_ROWS);
    out[OUT_AVG + t] = p;
    sP[t] = p * logf(p + 1e-10f);
    sL[t] = (t < N_ROWS / BLK) ? lossp[t] : 0.f;
    __syncthreads();
    for (int o = 512; o > 0; o >>= 1) {
        if (t < o) { sP[t] += sP[t + o]; sL[t] += sL[t + o]; }
        __syncthreads();
    }
    if (t == 0) {
        out[OUT_PPL] = expf(-sP[0]);
        out[OUT_LOSS] = 0.25f * (sL[0] * (1.0f / (float)(N_ROWS * C_DIM)));
    }
}

extern "C" void kernel_launch(void* const* d_in, const int* in_sizes, int n_in,
                              void* d_out, int out_size, void* d_ws, size_t ws_size,
                              hipStream_t stream) {
    const float* x = (const float*)d_in[0];
    const float* emb = (const float*)d_in[1];
    float* out = (float*)d_out;
    float* ws_f = (float*)d_ws;
    unsigned* ws_u = (unsigned*)d_ws;
    unsigned short* bs = (unsigned short*)(ws_u + WS_BS_D);
    unsigned short* pi1 = (unsigned short*)(ws_u + WS_PI1);

    vq_prep<<<N_ROWS / BLK, BLK, 0, stream>>>(emb, ws_f + WS_EE,
                                              ws_u + WS_HIST, bs);

    dim3 gM(N_ROWS / 128, 2);
    vq_mfma<<<gM, BLK, 0, stream>>>(x, bs, ws_f + WS_EE, ws_f + WS_PB1,
                                    ws_f + WS_PB2, pi1);

    vq_fused<<<N_ROWS / BLK, BLK, 0, stream>>>(x, emb, ws_f + WS_EE,
                                               ws_f + WS_PB1, ws_f + WS_PB2,
                                               pi1, ws_u + WS_HIST,
                                               ws_f + WS_LOSSP, out);

    vq_final<<<1, K_CODES, 0, stream>>>(ws_u + WS_HIST, ws_f + WS_LOSSP, out);
}

// Round 18
// 71.674 us; speedup vs baseline: 1.7904x; 1.7904x over previous
//
#include <hip/hip_runtime.h>
#include <math.h>
#include <float.h>

#define N_ROWS 65536
#define K_CODES 1024
#define C_DIM 64
#define BLK 256
#define TMARGIN 0.02f

typedef short s16x8 __attribute__((ext_vector_type(8)));
typedef float f32x4 __attribute__((ext_vector_type(4)));
typedef float f32x4u __attribute__((ext_vector_type(4), aligned(4)));

// d_out layout (float32), outputs concatenated in return order:
// [loss(1)][quantized_st(N*C)][perplexity(1)][indices(N)][avg_probs(K)]
#define OUT_LOSS 0
#define OUT_Q 1
#define OUT_PPL (1 + N_ROWS * C_DIM)     // 4194305
#define OUT_IDX (OUT_PPL + 1)            // 4194306
#define OUT_AVG (OUT_IDX + N_ROWS)       // 4259842

// d_ws layout (4-byte dword offsets), total 395,776 dw = 1.58 MB
#define WS_HIST 0                        // uint[1024]
#define WS_EE 1024                       // float[1024]
#define WS_LOSSP 2048                    // float[256]
#define WS_PB1 2560                      // float[2*N_ROWS]  -> 133632
#define WS_PB2 133632                    // float[2*N_ROWS]  -> 264704
#define WS_PI1 264704                    // ushort[2*N_ROWS] -> 330240
#define WS_BS_D 330240                   // ushort[1024*128] -> 395776

__device__ __forceinline__ unsigned short bf16_rne(float f) {
    unsigned u = __float_as_uint(f);
    return (unsigned short)((u + 0x7FFFu + ((u >> 16) & 1u)) >> 16);
}
__device__ __forceinline__ float bf16_val(unsigned short h) {
    return __uint_as_float(((unsigned)h) << 16);
}

// Kernel A: coalesced codebook split + hist zero + ee (verified order)
__global__ __launch_bounds__(BLK) void vq_prep(
    const float* __restrict__ emb, float* __restrict__ ee,
    unsigned* __restrict__ hist, unsigned short* __restrict__ bs) {
    const int gid = blockIdx.x * BLK + threadIdx.x;   // [0, 65536)
    {
        float e = emb[gid];                            // coalesced
        unsigned short h = bf16_rne(e);
        float m = e - bf16_val(h);
        int k = gid >> 6, c = gid & 63;
        bs[(size_t)k * 128 + c] = h;
        bs[(size_t)k * 128 + 64 + c] = bf16_rne(m);
    }
    if (gid < K_CODES) {
        hist[gid] = 0u;
        const float* ev = emb + (size_t)gid * C_DIM;
        float s0 = 0.f, s1 = 0.f, s2 = 0.f, s3 = 0.f;
#pragma unroll
        for (int i = 0; i < 16; ++i) {
            float a = ev[4 * i + 0], b = ev[4 * i + 1];
            float c = ev[4 * i + 2], d = ev[4 * i + 3];
            s0 = fmaf(a, a, s0);
            s1 = fmaf(b, b, s1);
            s2 = fmaf(c, c, s2);
            s3 = fmaf(d, d, s3);
        }
        ee[gid] = (s0 + s1) + (s2 + s3);
    }
}

// async global->LDS, 16B per lane; LDS dest is wave-uniform base + lane*16
#define GLD16(gsrc, ldst)                                                     \
    __builtin_amdgcn_global_load_lds(                                         \
        (const __attribute__((address_space(1))) unsigned int*)(gsrc),        \
        (__attribute__((address_space(3))) unsigned int*)(ldst), 16, 0, 0)

// Kernel B: MFMA distances — VERBATIM the measured-best R16 kernel (44.2 us):
// K-split x2, XOR swizzle, 4x3-MFMA chains, fmed3 2nd-best, 32-code phases
// (2 GLD16/phase, 16 barriers). R17's 64-code phase spilled (160+198 MB
// scratch traffic) — 32 is the phase-size sweet spot.
__global__ __launch_bounds__(BLK, 4) void vq_mfma(
    const float* __restrict__ x, const unsigned short* __restrict__ bs,
    const float* __restrict__ ee, float* __restrict__ pb1,
    float* __restrict__ pb2, unsigned short* __restrict__ pi1) {
    __shared__ __align__(16) unsigned char sB[2][8192];  // 2 x (32 codes x 256B)
    __shared__ float sEE[512];

    const int tid = threadIdx.x;
    const int wave = tid >> 6;
    const int lane = tid & 63;
    const int lrow = lane & 15;          // A-row / C-col lane index
    const int lq = lane >> 4;            // k-quarter / C row-group
    const int rowbase = blockIdx.x * 128 + wave * 32;
    const int half = blockIdx.y;
    const int kbase = half * (K_CODES / 2);

    sEE[tid] = ee[kbase + tid];
    sEE[tid + 256] = ee[kbase + tid + 256];

    // per-thread pre-swizzled global source for B staging (rule #21 pattern).
    const int srow = tid >> 4;
    const int sz8 = ((tid & 15) ^ (srow & 7)) * 8;       // ushort offset
    const unsigned short* sbase = bs + (size_t)(kbase + srow) * 128 + sz8;

    // ---- A fragments for two row-sets (P: rows 0..15, Q: rows 16..31) ----
    s16x8 ph0, ph1, pm0, pm1, qh0, qh1, qm0, qm1;
    {
        const float* xp = x + (size_t)(rowbase + lrow) * C_DIM + lq * 8;
        const float* xq = xp + 16 * C_DIM;
#pragma unroll
        for (int j = 0; j < 8; ++j) {
            float a0 = xp[j], a1 = xp[32 + j];
            float b0 = xq[j], b1v = xq[32 + j];
            unsigned short h;
            h = bf16_rne(a0); ph0[j] = (short)h; pm0[j] = (short)bf16_rne(a0 - bf16_val(h));
            h = bf16_rne(a1); ph1[j] = (short)h; pm1[j] = (short)bf16_rne(a1 - bf16_val(h));
            h = bf16_rne(b0); qh0[j] = (short)h; qm0[j] = (short)bf16_rne(b0 - bf16_val(h));
            h = bf16_rne(b1v); qh1[j] = (short)h; qm1[j] = (short)bf16_rne(b1v - bf16_val(h));
        }
    }

    float b1[8], b2[8];
    int i1[8];
#pragma unroll
    for (int q = 0; q < 8; ++q) { b1[q] = FLT_MAX; b2[q] = FLT_MAX; i1[q] = 0; }

    // swizzled ds_read byte offsets (within a 4KB sub-tile)
    const int rb = lrow * 256;
    const int swz = (lrow & 7) << 4;
    const int o0 = rb + ((0 + lq * 16) ^ swz);
    const int o1 = rb + ((64 + lq * 16) ^ swz);
    const int o2 = rb + ((128 + lq * 16) ^ swz);
    const int o3 = rb + ((192 + lq * 16) ^ swz);

    // prologue: stage phase 0 (32 codes = 8KB, two 4KB half-stages)
    GLD16(sbase, &sB[0][wave * 1024]);
    GLD16(sbase + 2048, &sB[0][4096 + wave * 1024]);
    __syncthreads();

    int buf = 0;
    for (int t = 0; t < 16; ++t) {          // 16 phases of 32 codes per half
        if (t + 1 < 16) {
            GLD16(sbase + (size_t)(t + 1) * 4096, &sB[buf ^ 1][wave * 1024]);
            GLD16(sbase + (size_t)(t + 1) * 4096 + 2048,
                  &sB[buf ^ 1][4096 + wave * 1024]);
        }

#pragma unroll
        for (int sub = 0; sub < 2; ++sub) {  // ascending code order kept
            const unsigned char* bb = &sB[buf][sub * 4096];
            s16x8 c0 = *(const s16x8*)(bb + o0);
            s16x8 c1 = *(const s16x8*)(bb + o1);
            s16x8 c2 = *(const s16x8*)(bb + o2);
            s16x8 c3 = *(const s16x8*)(bb + o3);
            float eek = sEE[t * 32 + sub * 16 + lrow];

            // x.e = xh.eh + xh.em + xm.eh, split by k-half: 4 chains of 3 MFMAs
            f32x4 z = {0.f, 0.f, 0.f, 0.f};
            f32x4 pa = __builtin_amdgcn_mfma_f32_16x16x32_bf16(ph0, c0, z, 0, 0, 0);
            f32x4 pb = __builtin_amdgcn_mfma_f32_16x16x32_bf16(ph1, c1, z, 0, 0, 0);
            f32x4 qa = __builtin_amdgcn_mfma_f32_16x16x32_bf16(qh0, c0, z, 0, 0, 0);
            f32x4 qb = __builtin_amdgcn_mfma_f32_16x16x32_bf16(qh1, c1, z, 0, 0, 0);
            pa = __builtin_amdgcn_mfma_f32_16x16x32_bf16(ph0, c2, pa, 0, 0, 0);
            pb = __builtin_amdgcn_mfma_f32_16x16x32_bf16(ph1, c3, pb, 0, 0, 0);
            qa = __builtin_amdgcn_mfma_f32_16x16x32_bf16(qh0, c2, qa, 0, 0, 0);
            qb = __builtin_amdgcn_mfma_f32_16x16x32_bf16(qh1, c3, qb, 0, 0, 0);
            pa = __builtin_amdgcn_mfma_f32_16x16x32_bf16(pm0, c0, pa, 0, 0, 0);
            pb = __builtin_amdgcn_mfma_f32_16x16x32_bf16(pm1, c1, pb, 0, 0, 0);
            qa = __builtin_amdgcn_mfma_f32_16x16x32_bf16(qm0, c0, qa, 0, 0, 0);
            qb = __builtin_amdgcn_mfma_f32_16x16x32_bf16(qm1, c1, qb, 0, 0, 0);

            const int code = kbase + t * 32 + sub * 16 + lrow;
#pragma unroll
            for (int q = 0; q < 4; ++q) {
                float sP = fmaf(-2.0f, pa[q] + pb[q], eek);
                b2[q] = __builtin_amdgcn_fmed3f(b1[q], b2[q], sP);  // new 2nd
                i1[q] = (sP < b1[q]) ? code : i1[q];      // strict <, asc code
                b1[q] = fminf(b1[q], sP);

                float sQ = fmaf(-2.0f, qa[q] + qb[q], eek);
                b2[4 + q] = __builtin_amdgcn_fmed3f(b1[4 + q], b2[4 + q], sQ);
                i1[4 + q] = (sQ < b1[4 + q]) ? code : i1[4 + q];
                b1[4 + q] = fminf(b1[4 + q], sQ);
            }
        }

        __syncthreads();
        buf ^= 1;
    }

    // cross-lane argmin over the 16 code-lanes (lex (score, idx)), keep top-2
#pragma unroll
    for (int m = 1; m <= 8; m <<= 1) {
#pragma unroll
        for (int q = 0; q < 8; ++q) {
            float ca = __shfl_xor(b1[q], m, 64);
            float cb = __shfl_xor(b2[q], m, 64);
            int ci = __shfl_xor(i1[q], m, 64);
            if (ca < b1[q] || (ca == b1[q] && ci < i1[q])) {
                b2[q] = fminf(b1[q], cb);
                b1[q] = ca;
                i1[q] = ci;
            } else {
                b2[q] = fminf(b2[q], ca);
            }
        }
    }

    if (lrow == 0) {
#pragma unroll
        for (int q = 0; q < 8; ++q) {
            int r = rowbase + (q >> 2) * 16 + lq * 4 + (q & 3);
            pb1[half * N_ROWS + r] = b1[q];
            pb2[half * N_ROWS + r] = b2[q];
            pi1[half * N_ROWS + r] = (unsigned short)i1[q];
        }
    }
}

// Kernel C (fused): merge halves + inline block-cooperative exact refine +
// histogram + indices + float4-vectorized quantized_st + loss partial.
__global__ __launch_bounds__(BLK) void vq_fused(
    const float* __restrict__ x, const float* __restrict__ emb,
    const float* __restrict__ ee, const float* __restrict__ pb1,
    const float* __restrict__ pb2, const unsigned short* __restrict__ pi1,
    unsigned* __restrict__ hist, float* __restrict__ lossp,
    float* __restrict__ out) {
    __shared__ int sIdx[BLK];
    __shared__ unsigned sHist[K_CODES];
    __shared__ float sRed[BLK / 64];
    __shared__ int sQ[BLK];
    __shared__ unsigned sQn;
    __shared__ float sWb[4];
    __shared__ int sWi[4];

    const int t = threadIdx.x;
    const int w = t >> 6;
    const int lane = t & 63;
    const int base = blockIdx.x * BLK;

    if (t == 0) sQn = 0u;
    for (int i = t; i < K_CODES; i += BLK) sHist[i] = 0u;

    // merge the two K-halves (verified logic: strict <, half0 wins ties)
    const int r = base + t;
    float a1 = pb1[r], a2 = pb2[r];
    int ai = pi1[r];
    float c1 = pb1[N_ROWS + r], c2 = pb2[N_ROWS + r];
    int ci = pi1[N_ROWS + r];
    bool bw = c1 < a1;
    float s1 = bw ? c1 : a1;
    int idx = bw ? ci : ai;
    float s2 = bw ? fminf(c2, a1) : fminf(a2, c1);
    sIdx[t] = idx;
    __syncthreads();                       // sQn/sHist/sIdx visible
    if (s2 - s1 < TMARGIN) {               // uncertain -> local queue
        unsigned p = atomicAdd(&sQn, 1u);
        sQ[p] = t;
    }
    __syncthreads();

    // inline exact re-argmin for queued rows (verified fp32 path; wave w owns
    // codes w*256 + lane*4 + j; lex block-reduce -> first-min semantics)
    const unsigned m = sQn;
    for (unsigned qi = 0; qi < m; ++qi) {
        const int rl = sQ[qi];
        const float4* xv = (const float4*)(x + (size_t)(base + rl) * C_DIM);
        float best = FLT_MAX;
        int bi = 0;
#pragma unroll
        for (int j = 0; j < 4; ++j) {
            const int k = w * 256 + lane * 4 + j;
            const float4* evv = (const float4*)(emb + (size_t)k * C_DIM);
            float d0 = 0.f, d1 = 0.f, d2 = 0.f, d3 = 0.f;
#pragma unroll
            for (int i = 0; i < 16; ++i) {
                float4 xi = xv[i];
                float4 e = evv[i];
                d0 = fmaf(xi.x, e.x, d0);
                d1 = fmaf(xi.y, e.y, d1);
                d2 = fmaf(xi.z, e.z, d2);
                d3 = fmaf(xi.w, e.w, d3);
            }
            float dot = (d0 + d1) + (d2 + d3);
            float s = fmaf(-2.0f, dot, ee[k]);
            if (s < best) { best = s; bi = k; }      // strict <: first-min
        }
#pragma unroll
        for (int mm = 1; mm <= 32; mm <<= 1) {
            float ob = __shfl_xor(best, mm, 64);
            int oi = __shfl_xor(bi, mm, 64);
            if (ob < best || (ob == best && oi < bi)) { best = ob; bi = oi; }
        }
        if (lane == 0) { sWb[w] = best; sWi[w] = bi; }
        __syncthreads();
        if (t == 0) {
            float b = sWb[0];
            int i = sWi[0];
#pragma unroll
            for (int w2 = 1; w2 < 4; ++w2) {
                if (sWb[w2] < b || (sWb[w2] == b && sWi[w2] < i)) {
                    b = sWb[w2];
                    i = sWi[w2];
                }
            }
            sIdx[rl] = i;
        }
        __syncthreads();
    }

    // indices out + histogram (final indices)
    const int bidx = sIdx[t];
    out[OUT_IDX + r] = (float)bidx;
    atomicAdd(&sHist[bidx], 1u);
    __syncthreads();
    for (int i = t; i < K_CODES; i += BLK) {
        unsigned c = sHist[i];
        if (c) atomicAdd(&hist[i], c);
    }

    // epilogue: quantized_st + loss partial, float4-vectorized:
    // 16 threads per row x 4 floats; 16 iterations (was 64 scalar).
    float lsum = 0.f;
    const int c4 = (t & 15) * 4;           // column (float4 granularity)
    const int rg4 = t >> 4;                // row group 0..15
    for (int it = 0; it < 16; ++it) {
        const int rl = it * 16 + rg4;
        const int rr = base + rl;
        const int bi = sIdx[rl];           // uniform per 16-lane group
        float4 xv = *(const float4*)(x + (size_t)rr * C_DIM + c4);
        float4 qv = *(const float4*)(emb + (size_t)bi * C_DIM + c4);
        float dx = qv.x - xv.x, dy = qv.y - xv.y;
        float dz = qv.z - xv.z, dw = qv.w - xv.w;
        f32x4u o;
        o[0] = xv.x + dx; o[1] = xv.y + dy;
        o[2] = xv.z + dz; o[3] = xv.w + dw;          // straight-through
        *(f32x4u*)(out + OUT_Q + (size_t)rr * C_DIM + c4) = o;
        lsum = fmaf(dx, dx, lsum);
        lsum = fmaf(dy, dy, lsum);
        lsum = fmaf(dz, dz, lsum);
        lsum = fmaf(dw, dw, lsum);
    }
#pragma unroll
    for (int o = 32; o > 0; o >>= 1) lsum += __shfl_down(lsum, o, 64);
    if ((t & 63) == 0) sRed[t >> 6] = lsum;
    __syncthreads();
    if (t == 0) lossp[blockIdx.x] = (sRed[0] + sRed[1]) + (sRed[2] + sRed[3]);
}

// Kernel D: avg_probs, perplexity, loss finalization
__global__ void vq_final(const unsigned* __restrict__ hist,
                         const float* __restrict__ lossp,
                         float* __restrict__ out) {
    __shared__ float sP[K_CODES];
    __shared__ float sL[K_CODES];
    const int t = threadIdx.x;
    float p = (float)hist[t] * (1.0f / (float)N_ROWS);
    out[OUT_AVG + t] = p;
    sP[t] = p * logf(p + 1e-10f);
    sL[t] = (t < N_ROWS / BLK) ? lossp[t] : 0.f;
    __syncthreads();
    for (int o = 512; o > 0; o >>= 1) {
        if (t < o) { sP[t] += sP[t + o]; sL[t] += sL[t + o]; }
        __syncthreads();
    }
    if (t == 0) {
        out[OUT_PPL] = expf(-sP[0]);
        out[OUT_LOSS] = 0.25f * (sL[0] * (1.0f / (float)(N_ROWS * C_DIM)));
    }
}

extern "C" void kernel_launch(void* const* d_in, const int* in_sizes, int n_in,
                              void* d_out, int out_size, void* d_ws, size_t ws_size,
                              hipStream_t stream) {
    const float* x = (const float*)d_in[0];
    const float* emb = (const float*)d_in[1];
    float* out = (float*)d_out;
    float* ws_f = (float*)d_ws;
    unsigned* ws_u = (unsigned*)d_ws;
    unsigned short* bs = (unsigned short*)(ws_u + WS_BS_D);
    unsigned short* pi1 = (unsigned short*)(ws_u + WS_PI1);

    vq_prep<<<N_ROWS / BLK, BLK, 0, stream>>>(emb, ws_f + WS_EE,
                                              ws_u + WS_HIST, bs);

    dim3 gM(N_ROWS / 128, 2);
    vq_mfma<<<gM, BLK, 0, stream>>>(x, bs, ws_f + WS_EE, ws_f + WS_PB1,
                                    ws_f + WS_PB2, pi1);

    vq_fused<<<N_ROWS / BLK, BLK, 0, stream>>>(x, emb, ws_f + WS_EE,
                                               ws_f + WS_PB1, ws_f + WS_PB2,
                                               pi1, ws_u + WS_HIST,
                                               ws_f + WS_LOSSP, out);

    vq_final<<<1, K_CODES, 0, stream>>>(ws_u + WS_HIST, ws_f + WS_LOSSP, out);
}